// Round 6
// baseline (3256.007 us; speedup 1.0000x reference)
//
#include <hip/hip_runtime.h>
#include <hip/hip_bf16.h>

// STDP IF-neuron network, T=50 sequential steps. Persistent-kernel v3.
// x_seq [50,256,1024] f32, weight [2048,1024] f32 -> spike_trace [256,2048] f32.
//
// 128 blocks x 1024 thr (16 waves, 4/SIMD); block owns a 16-h slab for all
// 50 steps. W bf16 hi/lo splits in LDS (XOR-swizzled); W fp32 master in
// registers (4x f32x4/thread); v, trace in registers; s in LDS. 2 barriers
// per step. v2's lesson: __launch_bounds__(512,2) capped VGPR at 128 and
// spilled the pipeline frags to scratch (WRITE_SIZE 23 MB). v3 halves
// per-wave frag state (1 b-tile/wave fwd, half-group wupd pipeline) so
// everything fits in 128 VGPRs at 4 waves/SIMD.
//
// fwd: mem = x @ W^T, 3-product bf16 split (hh+hl+lh), A-frags from global
//      (L2-resident), ping-pong 4-chunk groups (8-16 loads in flight/wave).
// wupd: dwT = xT @ s^T via mfma(A=xT, B=s); half-group (4 b-chunk) ping-pong.
// Product sets and accumulation orders identical to rounds 2-5 -> bit-
// identical output (absmax 1.0 regime preserved).

#define T_STEPS 50
#define BATCH   256
#define DIM     1024
#define HID     2048
#define HT      16
#define LR_OVER_B (0.005f / 256.0f)

// LDS: wh u16[16][1024] swz | wl u16[16][1024] swz | s u16[16][256] swz
#define SMEM_BYTES (32768 + 32768 + 8192)

typedef __attribute__((ext_vector_type(8))) short short8v;
typedef __attribute__((ext_vector_type(4))) float f32x4;

static __device__ __forceinline__ ushort f32_to_bf16u(float f) {
    __hip_bfloat16 h = __float2bfloat16(f);
    return __builtin_bit_cast(unsigned short, h);
}
static __device__ __forceinline__ float bf16u_to_f32(ushort u) {
    __hip_bfloat16 h = __builtin_bit_cast(__hip_bfloat16, u);
    return __bfloat162float(h);
}

#define MFMA_B16 __builtin_amdgcn_mfma_f32_16x16x32_bf16

// ---------------- prep: row-major + transposed bf16 splits of x -----------
__global__ __launch_bounds__(256) void prep_x(
    const float* __restrict__ x,
    ushort* __restrict__ xh,  ushort* __restrict__ xl,    // [T,B,D]
    ushort* __restrict__ xTh, ushort* __restrict__ xTl)   // [T,D,B]
{
    __shared__ float tile[32][33];
    const int t  = blockIdx.z;
    const int d0 = blockIdx.x * 32;
    const int b0 = blockIdx.y * 32;
    const int tx = threadIdx.x & 31;
    const int ty = threadIdx.x >> 5;         // 0..7
    const float* xt = x + (size_t)t * BATCH * DIM;
    ushort* xht = xh + (size_t)t * BATCH * DIM;
    ushort* xlt = xl + (size_t)t * BATCH * DIM;
#pragma unroll
    for (int r = 0; r < 32; r += 8) {
        size_t gi = (size_t)(b0 + ty + r) * DIM + d0 + tx;
        float v = xt[gi];
        tile[ty + r][tx] = v;
        ushort hi = f32_to_bf16u(v);
        xht[gi] = hi;
        xlt[gi] = f32_to_bf16u(v - bf16u_to_f32(hi));
    }
    __syncthreads();
    ushort* oth = xTh + (size_t)t * DIM * BATCH;
    ushort* otl = xTl + (size_t)t * DIM * BATCH;
#pragma unroll
    for (int r = 0; r < 32; r += 8) {
        float v = tile[tx][ty + r];          // d = d0+ty+r, b = b0+tx
        ushort hi = f32_to_bf16u(v);
        size_t gi = (size_t)(d0 + ty + r) * BATCH + b0 + tx;
        oth[gi] = hi;
        otl[gi] = f32_to_bf16u(v - bf16u_to_f32(hi));
    }
}

// ---------------- THE persistent kernel -----------------------------------
__global__ __launch_bounds__(1024, 1) void stdp_persistent(
    const ushort* __restrict__ xh,  const ushort* __restrict__ xl,   // [T,B,D]
    const ushort* __restrict__ xTh, const ushort* __restrict__ xTl,  // [T,D,B]
    const float* __restrict__ weight,                                 // [H,D]
    float* __restrict__ out)                                          // [B,H]
{
    extern __shared__ char smem[];
    ushort* wh = (ushort*)smem;                    // [16][1024] swizzled
    ushort* wl = (ushort*)(smem + 32768);          // [16][1024] swizzled
    ushort* sl = (ushort*)(smem + 65536);          // [16][256]  swizzled

    const int tid  = threadIdx.x;
    const int lane = tid & 63;
    const int w    = tid >> 6;                     // wave 0..15
    const int h0   = blockIdx.x * HT;

    const int fr  = lane & 15;                     // fragment row / h index
    const int kg  = (lane >> 4) * 8;               // fragment k-group offset
    const int rq  = (lane >> 4) * 4;               // D-fragment row base
    const int fsw = (fr & 7) << 3;                 // LDS XOR swizzle

    // ---- init: W master -> registers; bf16 splits -> swizzled LDS ----
    // lane owns h = h0+fr, d = w*64 + tile*16 + rq + {0..3}, tile 0..3
    f32x4 wreg[4];
#pragma unroll
    for (int tile = 0; tile < 4; ++tile) {
        const int d = w * 64 + tile * 16 + rq;
        float4 wv = *(const float4*)&weight[(size_t)(h0 + fr) * DIM + d];
        wreg[tile][0] = wv.x; wreg[tile][1] = wv.y;
        wreg[tile][2] = wv.z; wreg[tile][3] = wv.w;
        ushort4 hi4, lo4;
        ushort* hp = &hi4.x; ushort* lp = &lo4.x;
        const float* p = &wv.x;
#pragma unroll
        for (int e = 0; e < 4; ++e) {
            ushort hb = f32_to_bf16u(p[e]);
            hp[e] = hb;
            lp[e] = f32_to_bf16u(p[e] - bf16u_to_f32(hb));
        }
        const int sidx = (fr << 10) | (d ^ fsw);
        *(ushort4*)&wh[sidx] = hi4;
        *(ushort4*)&wl[sidx] = lo4;
    }
    __syncthreads();

    const f32x4 z4 = {0.f, 0.f, 0.f, 0.f};
    f32x4 vmem = z4;
    f32x4 trc  = z4;

    for (int t = 0; t < T_STEPS; ++t) {
        const ushort* xht = xh + (size_t)t * BATCH * DIM;
        const ushort* xlt = xl + (size_t)t * BATCH * DIM;

        // ================= fwd: mem = x @ W^T (3-product split) ===========
        // wave w owns b rows [16w, 16w+16); 1 b-tile, acc single f32x4.
        f32x4 acc = z4;
        const size_t r0 = (size_t)(w * 16 + fr) * DIM + kg;

        short8v GA[4][2], GB[4][2];   // 4-chunk groups (k-span 128), hi/lo

#define LDA(F, kbase) do { _Pragma("unroll") \
    for (int c = 0; c < 4; ++c) { \
        const int kk_ = (kbase) + c * 32; \
        F[c][0] = *(const short8v*)&xht[r0 + kk_]; \
        F[c][1] = *(const short8v*)&xlt[r0 + kk_]; } } while (0)

#define MFG(F, kbase) do { _Pragma("unroll") \
    for (int c = 0; c < 4; ++c) { \
        const int kk_ = (kbase) + c * 32; \
        const int bi_ = (fr << 10) | ((kk_ + kg) ^ fsw); \
        short8v bh_ = *(const short8v*)&wh[bi_]; \
        short8v bl_ = *(const short8v*)&wl[bi_]; \
        acc = MFMA_B16(F[c][0], bh_, acc, 0, 0, 0); \
        acc = MFMA_B16(F[c][0], bl_, acc, 0, 0, 0); \
        acc = MFMA_B16(F[c][1], bh_, acc, 0, 0, 0); } } while (0)

        LDA(GA, 0);
        LDA(GB, 128);
#pragma unroll
        for (int i = 0; i < 4; ++i) {
            MFG(GA, i * 256);
            if (i < 3) LDA(GA, (i + 1) * 256);
            MFG(GB, i * 256 + 128);
            if (i < 3) LDA(GB, (i + 1) * 256 + 128);
        }
#undef LDA
#undef MFG

        // ---- fused IF update + packed spike store (D: row=b, col=h) ----
        {
            const int bb = w * 16 + rq;
            ushort4 sq; ushort* sp = &sq.x;
#pragma unroll
            for (int j = 0; j < 4; ++j) {
                float nv = vmem[j] + acc[j];
                bool fire = (nv >= 1.0f);
                vmem[j] = fire ? 0.0f : nv;
                trc[j] += fire ? 1.0f : 0.0f;
                sp[j] = fire ? (ushort)0x3F80 : (ushort)0;
            }
            *(ushort4*)&sl[(fr << 8) | (bb ^ fsw)] = sq;
        }

        __syncthreads();   // barrier 1: s complete; fwd W-reads done

        // ================= wupd: dwT = xT @ s^T, W += lr/B * dw ===========
        // wave w owns d rows [64w, 64w+64) = 4 d-tiles of 16.
        if (t < T_STEPS - 1) {
            const ushort* xTht = xTh + (size_t)t * DIM * BATCH;
            const ushort* xTlt = xTl + (size_t)t * DIM * BATCH;

            short8v HA[4][2], HB[4][2];   // half-groups: 4 b-chunks, hi/lo

#define LDH(F, T, H) do { _Pragma("unroll") \
    for (int c2 = 0; c2 < 4; ++c2) { \
        const size_t gi_ = (size_t)(w * 64 + (T) * 16 + fr) * BATCH \
                         + ((H) * 4 + c2) * 32 + kg; \
        F[c2][0] = *(const short8v*)&xTht[gi_]; \
        F[c2][1] = *(const short8v*)&xTlt[gi_]; } } while (0)

// consumes half-group F (b-chunks H*4..H*4+3); s-frags read per-chunk from LDS
#define MFH(F, H) do { _Pragma("unroll") \
    for (int c2 = 0; c2 < 4; ++c2) { \
        const int c_ = (H) * 4 + c2; \
        short8v sf_ = *(const short8v*)&sl[(fr << 8) | ((c_ * 32 + kg) ^ fsw)]; \
        du = MFMA_B16(F[c2][0], sf_, du, 0, 0, 0); \
        du = MFMA_B16(F[c2][1], sf_, du, 0, 0, 0); } } while (0)

#define WST(T) do { \
    const int d_ = w * 64 + (T) * 16 + rq; \
    ushort4 hi4, lo4; ushort* hp_ = &hi4.x; ushort* lp_ = &lo4.x; \
    _Pragma("unroll") \
    for (int j = 0; j < 4; ++j) { \
        float wv_ = fmaf(LR_OVER_B, du[j], wreg[T][j]); \
        wreg[T][j] = wv_; \
        ushort hb_ = f32_to_bf16u(wv_); \
        hp_[j] = hb_; \
        lp_[j] = f32_to_bf16u(wv_ - bf16u_to_f32(hb_)); } \
    const int si_ = (fr << 10) | (d_ ^ fsw); \
    *(ushort4*)&wh[si_] = hi4; \
    *(ushort4*)&wl[si_] = lo4; } while (0)

            LDH(HA, 0, 0);
            LDH(HB, 0, 1);
            {
                f32x4 du = z4;
                MFH(HA, 0); LDH(HA, 1, 0);
                MFH(HB, 1); LDH(HB, 1, 1);
                WST(0);
            }
            {
                f32x4 du = z4;
                MFH(HA, 0); LDH(HA, 2, 0);
                MFH(HB, 1); LDH(HB, 2, 1);
                WST(1);
            }
            {
                f32x4 du = z4;
                MFH(HA, 0); LDH(HA, 3, 0);
                MFH(HB, 1); LDH(HB, 3, 1);
                WST(2);
            }
            {
                f32x4 du = z4;
                MFH(HA, 0);
                MFH(HB, 1);
                WST(3);
            }
#undef LDH
#undef MFH
#undef WST
        }

        __syncthreads();   // barrier 2: wh/wl consistent for next fwd
    }

    // ---- write trace (registers) to d_out [B,H] ----
#pragma unroll
    for (int j = 0; j < 4; ++j) {
        int b = w * 16 + rq + j;
        out[(size_t)b * HID + h0 + fr] = trc[j];
    }
}

// ---------------- fallback fp32 kernels (round-0, small ws) ---------------
#define BK 16
__global__ __launch_bounds__(256) void stdp_fwd_if(
    const float* __restrict__ x, const float* __restrict__ w,
    float* __restrict__ v, float* __restrict__ s, float* __restrict__ trace)
{
    __shared__ float as[BK][64];
    __shared__ float bs[BK][64];
    const int tid = threadIdx.x;
    const int tx = tid & 15, ty = tid >> 4;
    const int b0 = blockIdx.y * 64, h0 = blockIdx.x * 64;
    const int row = tid >> 2, kq = (tid & 3) * 4;
    float acc[4][4] = {};
    for (int k0 = 0; k0 < DIM; k0 += BK) {
        float4 ga = *(const float4*)&x[(size_t)(b0 + row) * DIM + k0 + kq];
        float4 gb = *(const float4*)&w[(size_t)(h0 + row) * DIM + k0 + kq];
        __syncthreads();
        as[kq + 0][row] = ga.x; as[kq + 1][row] = ga.y;
        as[kq + 2][row] = ga.z; as[kq + 3][row] = ga.w;
        bs[kq + 0][row] = gb.x; bs[kq + 1][row] = gb.y;
        bs[kq + 2][row] = gb.z; bs[kq + 3][row] = gb.w;
        __syncthreads();
#pragma unroll
        for (int kk = 0; kk < BK; ++kk) {
            float4 af = *(const float4*)&as[kk][ty * 4];
            float4 bf = *(const float4*)&bs[kk][tx * 4];
            float av[4] = {af.x, af.y, af.z, af.w};
            float bv[4] = {bf.x, bf.y, bf.z, bf.w};
#pragma unroll
            for (int m = 0; m < 4; ++m)
#pragma unroll
                for (int n = 0; n < 4; ++n)
                    acc[m][n] = fmaf(av[m], bv[n], acc[m][n]);
        }
    }
#pragma unroll
    for (int m = 0; m < 4; ++m) {
        size_t idx = (size_t)(b0 + ty * 4 + m) * HID + h0 + tx * 4;
        float4 vv = *(float4*)&v[idx];
        float4 tr = *(float4*)&trace[idx];
        float4 sv;
        float* vvp = &vv.x; float* trp = &tr.x; float* svp = &sv.x;
#pragma unroll
        for (int n = 0; n < 4; ++n) {
            float nv = vvp[n] + acc[m][n];
            float sp = (nv >= 1.0f) ? 1.0f : 0.0f;
            vvp[n] = (nv >= 1.0f) ? 0.0f : nv;
            svp[n] = sp; trp[n] += sp;
        }
        *(float4*)&v[idx] = vv;
        *(float4*)&s[idx] = sv;
        *(float4*)&trace[idx] = tr;
    }
}

__global__ __launch_bounds__(256) void stdp_wupd(
    const float* __restrict__ x, const float* __restrict__ s,
    float* __restrict__ w)
{
    __shared__ float ss[BK][64];
    __shared__ float xs[BK][64];
    const int tid = threadIdx.x;
    const int tx = tid & 15, ty = tid >> 4;
    const int h0 = blockIdx.y * 64, d0 = blockIdx.x * 64;
    const int krow = tid >> 4, c4 = (tid & 15) * 4;
    float acc[4][4] = {};
    for (int bk0 = 0; bk0 < BATCH; bk0 += BK) {
        float4 gs = *(const float4*)&s[(size_t)(bk0 + krow) * HID + h0 + c4];
        float4 gx = *(const float4*)&x[(size_t)(bk0 + krow) * DIM + d0 + c4];
        __syncthreads();
        *(float4*)&ss[krow][c4] = gs;
        *(float4*)&xs[krow][c4] = gx;
        __syncthreads();
#pragma unroll
        for (int kk = 0; kk < BK; ++kk) {
            float4 af = *(const float4*)&ss[kk][ty * 4];
            float4 bf = *(const float4*)&xs[kk][tx * 4];
            float av[4] = {af.x, af.y, af.z, af.w};
            float bv[4] = {bf.x, bf.y, bf.z, bf.w};
#pragma unroll
            for (int m = 0; m < 4; ++m)
#pragma unroll
                for (int n = 0; n < 4; ++n)
                    acc[m][n] = fmaf(av[m], bv[n], acc[m][n]);
        }
    }
#pragma unroll
    for (int m = 0; m < 4; ++m) {
        size_t idx = (size_t)(h0 + ty * 4 + m) * DIM + d0 + tx * 4;
        float4 wv = *(float4*)&w[idx];
        wv.x = fmaf(LR_OVER_B, acc[m][0], wv.x);
        wv.y = fmaf(LR_OVER_B, acc[m][1], wv.y);
        wv.z = fmaf(LR_OVER_B, acc[m][2], wv.z);
        wv.w = fmaf(LR_OVER_B, acc[m][3], wv.w);
        *(float4*)&w[idx] = wv;
    }
}

extern "C" void kernel_launch(void* const* d_in, const int* in_sizes, int n_in,
                              void* d_out, int out_size, void* d_ws, size_t ws_size,
                              hipStream_t stream) {
    (void)in_sizes; (void)n_in;
    const float* x_seq  = (const float*)d_in[0];   // [T, B, D]
    const float* weight = (const float*)d_in[1];   // [H, D]
    float* out = (float*)d_out;                    // [B, H]

    const size_t WN = (size_t)HID * DIM;
    const size_t BH = (size_t)BATCH * HID;
    const size_t XN = (size_t)T_STEPS * BATCH * DIM;  // 13107200

    const size_t need = 4 * XN * 2;                // xh | xl | xTh | xTl

    if (ws_size >= need) {
        ushort* xh  = (ushort*)d_ws;
        ushort* xl  = xh + XN;
        ushort* xTh = xl + XN;
        ushort* xTl = xTh + XN;

        prep_x<<<dim3(DIM / 32, BATCH / 32, T_STEPS), 256, 0, stream>>>(
            x_seq, xh, xl, xTh, xTl);

        hipFuncSetAttribute(reinterpret_cast<const void*>(&stdp_persistent),
                            hipFuncAttributeMaxDynamicSharedMemorySize,
                            SMEM_BYTES);
        stdp_persistent<<<HID / HT, 1024, SMEM_BYTES, stream>>>(
            xh, xl, xTh, xTl, weight, out);
    } else {
        // fallback: fp32 VALU path (needs ~12.6 MB)
        float* w = (float*)d_ws;
        float* v = w + WN;
        float* s = v + BH;
        hipMemcpyAsync(w, weight, WN * 4, hipMemcpyDeviceToDevice, stream);
        hipMemsetAsync(v, 0, BH * 4, stream);
        hipMemsetAsync(out, 0, (size_t)out_size * 4, stream);
        dim3 blkA(256), grdA(HID / 64, BATCH / 64);
        dim3 blkB(256), grdB(DIM / 64, HID / 64);
        for (int t = 0; t < T_STEPS; ++t) {
            const float* xt = x_seq + (size_t)t * BATCH * DIM;
            stdp_fwd_if<<<grdA, blkA, 0, stream>>>(xt, w, v, s, out);
            if (t < T_STEPS - 1) {
                stdp_wupd<<<grdB, blkB, 0, stream>>>(xt, s, w);
            }
        }
    }
}

// Round 7
// 2922.314 us; speedup vs baseline: 1.1142x; 1.1142x over previous
//
#include <hip/hip_runtime.h>
#include <hip/hip_bf16.h>

// STDP IF-neuron network, T=50 sequential steps. Persistent-kernel v4.
// x_seq [50,256,1024] f32, weight [2048,1024] f32 -> spike_trace [256,2048] f32.
//
// 128 blocks x 1024 thr (16 waves = 4/SIMD); block owns a 16-h slab for all
// 50 steps. W bf16 hi/lo splits in LDS (XOR-swizzled, 64 KB); W fp32 master
// in registers (4x f32x4/thread); v, trace in registers; s in LDS (8 KB).
// 2 block-local barriers/step. Zero W global traffic.
//
// v2/v3 lesson: oversized per-wave pipeline state spilled to scratch
// (VGPR cap 128 @ v2, 64 @ v3 -> WRITE_SIZE 23/42 MB, 2.9/3.3 ms).
// v4: __launch_bounds__(1024,4) pins the 128-VGPR budget explicitly, and
// all load groups are SINGLE-buffered (GA[4][2] = 32 VGPR peak) -> ~90
// live regs, no spill. Latency hiding via 16 desynced waves/CU (TLP),
// not per-wave ILP depth.
//
// fwd:  mem = x @ W^T, 3-product bf16 split (hh+hl+lh), A-frags from
//       global (L2/L3-resident x), 8 groups of 4 k-chunks.
// wupd: dwT = xT @ s^T via mfma(A=xT, B=s); 4 d-tiles x 2 half-groups.
// Product set and accumulation order identical to rounds 2-6 -> bit-
// identical output (absmax 1.0 regime preserved).

#define T_STEPS 50
#define BATCH   256
#define DIM     1024
#define HID     2048
#define HT      16
#define LR_OVER_B (0.005f / 256.0f)

// LDS: wh u16[16][1024] swz | wl u16[16][1024] swz | s u16[16][256] swz
#define SMEM_BYTES (32768 + 32768 + 8192)

typedef __attribute__((ext_vector_type(8))) short short8v;
typedef __attribute__((ext_vector_type(4))) float f32x4;

static __device__ __forceinline__ ushort f32_to_bf16u(float f) {
    __hip_bfloat16 h = __float2bfloat16(f);
    return __builtin_bit_cast(unsigned short, h);
}
static __device__ __forceinline__ float bf16u_to_f32(ushort u) {
    __hip_bfloat16 h = __builtin_bit_cast(__hip_bfloat16, u);
    return __bfloat162float(h);
}

#define MFMA_B16 __builtin_amdgcn_mfma_f32_16x16x32_bf16

// ---------------- prep: row-major + transposed bf16 splits of x -----------
__global__ __launch_bounds__(256) void prep_x(
    const float* __restrict__ x,
    ushort* __restrict__ xh,  ushort* __restrict__ xl,    // [T,B,D]
    ushort* __restrict__ xTh, ushort* __restrict__ xTl)   // [T,D,B]
{
    __shared__ float tile[32][33];
    const int t  = blockIdx.z;
    const int d0 = blockIdx.x * 32;
    const int b0 = blockIdx.y * 32;
    const int tx = threadIdx.x & 31;
    const int ty = threadIdx.x >> 5;         // 0..7
    const float* xt = x + (size_t)t * BATCH * DIM;
    ushort* xht = xh + (size_t)t * BATCH * DIM;
    ushort* xlt = xl + (size_t)t * BATCH * DIM;
#pragma unroll
    for (int r = 0; r < 32; r += 8) {
        size_t gi = (size_t)(b0 + ty + r) * DIM + d0 + tx;
        float v = xt[gi];
        tile[ty + r][tx] = v;
        ushort hi = f32_to_bf16u(v);
        xht[gi] = hi;
        xlt[gi] = f32_to_bf16u(v - bf16u_to_f32(hi));
    }
    __syncthreads();
    ushort* oth = xTh + (size_t)t * DIM * BATCH;
    ushort* otl = xTl + (size_t)t * DIM * BATCH;
#pragma unroll
    for (int r = 0; r < 32; r += 8) {
        float v = tile[tx][ty + r];          // d = d0+ty+r, b = b0+tx
        ushort hi = f32_to_bf16u(v);
        size_t gi = (size_t)(d0 + ty + r) * BATCH + b0 + tx;
        oth[gi] = hi;
        otl[gi] = f32_to_bf16u(v - bf16u_to_f32(hi));
    }
}

// ---------------- THE persistent kernel -----------------------------------
__global__ __launch_bounds__(1024, 4) void stdp_persistent(
    const ushort* __restrict__ xh,  const ushort* __restrict__ xl,   // [T,B,D]
    const ushort* __restrict__ xTh, const ushort* __restrict__ xTl,  // [T,D,B]
    const float* __restrict__ weight,                                 // [H,D]
    float* __restrict__ out)                                          // [B,H]
{
    extern __shared__ char smem[];
    ushort* wh = (ushort*)smem;                    // [16][1024] swizzled
    ushort* wl = (ushort*)(smem + 32768);          // [16][1024] swizzled
    ushort* sl = (ushort*)(smem + 65536);          // [16][256]  swizzled

    const int tid  = threadIdx.x;
    const int lane = tid & 63;
    const int w    = tid >> 6;                     // wave 0..15
    const int h0   = blockIdx.x * HT;

    const int fr  = lane & 15;                     // fragment row / h index
    const int kg  = (lane >> 4) * 8;               // fragment k-group offset
    const int rq  = (lane >> 4) * 4;               // D-fragment row base
    const int fsw = (fr & 7) << 3;                 // LDS XOR swizzle

    // ---- init: W master -> registers; bf16 splits -> swizzled LDS ----
    // lane owns h = h0+fr, d = w*64 + tile*16 + rq + {0..3}, tile 0..3
    f32x4 wreg[4];
#pragma unroll
    for (int tile = 0; tile < 4; ++tile) {
        const int d = w * 64 + tile * 16 + rq;
        float4 wv = *(const float4*)&weight[(size_t)(h0 + fr) * DIM + d];
        wreg[tile][0] = wv.x; wreg[tile][1] = wv.y;
        wreg[tile][2] = wv.z; wreg[tile][3] = wv.w;
        ushort4 hi4, lo4;
        ushort* hp = &hi4.x; ushort* lp = &lo4.x;
        const float* p = &wv.x;
#pragma unroll
        for (int e = 0; e < 4; ++e) {
            ushort hb = f32_to_bf16u(p[e]);
            hp[e] = hb;
            lp[e] = f32_to_bf16u(p[e] - bf16u_to_f32(hb));
        }
        const int sidx = (fr << 10) | (d ^ fsw);
        *(ushort4*)&wh[sidx] = hi4;
        *(ushort4*)&wl[sidx] = lo4;
    }
    __syncthreads();

    const f32x4 z4 = {0.f, 0.f, 0.f, 0.f};
    f32x4 vmem = z4;
    f32x4 trc  = z4;

    for (int t = 0; t < T_STEPS; ++t) {
        const ushort* xht = xh + (size_t)t * BATCH * DIM;
        const ushort* xlt = xl + (size_t)t * BATCH * DIM;

        // ================= fwd: mem = x @ W^T (3-product split) ===========
        // wave w owns b rows [16w, 16w+16); single-buffered 4-chunk groups.
        f32x4 acc = z4;
        const size_t r0 = (size_t)(w * 16 + fr) * DIM + kg;

        short8v GA[4][2];   // 4 k-chunks (k-span 128), hi/lo

#pragma unroll
        for (int g = 0; g < 8; ++g) {
            const int kbase = g * 128;
#pragma unroll
            for (int c = 0; c < 4; ++c) {
                const int kk = kbase + c * 32;
                GA[c][0] = *(const short8v*)&xht[r0 + kk];
                GA[c][1] = *(const short8v*)&xlt[r0 + kk];
            }
#pragma unroll
            for (int c = 0; c < 4; ++c) {
                const int kk = kbase + c * 32;
                const int bi = (fr << 10) | ((kk + kg) ^ fsw);
                short8v bh = *(const short8v*)&wh[bi];
                short8v bl = *(const short8v*)&wl[bi];
                acc = MFMA_B16(GA[c][0], bh, acc, 0, 0, 0);
                acc = MFMA_B16(GA[c][0], bl, acc, 0, 0, 0);
                acc = MFMA_B16(GA[c][1], bh, acc, 0, 0, 0);
            }
        }

        // ---- fused IF update + packed spike store (D: row=b, col=h) ----
        {
            const int bb = w * 16 + rq;
            ushort4 sq; ushort* sp = &sq.x;
#pragma unroll
            for (int j = 0; j < 4; ++j) {
                float nv = vmem[j] + acc[j];
                bool fire = (nv >= 1.0f);
                vmem[j] = fire ? 0.0f : nv;
                trc[j] += fire ? 1.0f : 0.0f;
                sp[j] = fire ? (ushort)0x3F80 : (ushort)0;
            }
            *(ushort4*)&sl[(fr << 8) | (bb ^ fsw)] = sq;
        }

        __syncthreads();   // barrier 1: s complete; fwd W-reads done

        // ================= wupd: dwT = xT @ s^T, W += lr/B * dw ===========
        // wave w owns d rows [64w, 64w+64) = 4 d-tiles of 16.
        if (t < T_STEPS - 1) {
            const ushort* xTht = xTh + (size_t)t * DIM * BATCH;
            const ushort* xTlt = xTl + (size_t)t * DIM * BATCH;

            short8v HA[4][2];   // half-group: 4 b-chunks, hi/lo

#pragma unroll
            for (int tile = 0; tile < 4; ++tile) {
                f32x4 du = z4;
                const size_t drow = (size_t)(w * 64 + tile * 16 + fr) * BATCH;
#pragma unroll
                for (int half = 0; half < 2; ++half) {
#pragma unroll
                    for (int c2 = 0; c2 < 4; ++c2) {
                        const size_t gi = drow + (half * 4 + c2) * 32 + kg;
                        HA[c2][0] = *(const short8v*)&xTht[gi];
                        HA[c2][1] = *(const short8v*)&xTlt[gi];
                    }
#pragma unroll
                    for (int c2 = 0; c2 < 4; ++c2) {
                        const int c = half * 4 + c2;
                        short8v sf = *(const short8v*)&sl[(fr << 8) | ((c * 32 + kg) ^ fsw)];
                        du = MFMA_B16(HA[c2][0], sf, du, 0, 0, 0);
                        du = MFMA_B16(HA[c2][1], sf, du, 0, 0, 0);
                    }
                }
                // ---- W update + re-split (D: row=d, col=h=fr) ----
                const int d = w * 64 + tile * 16 + rq;
                ushort4 hi4, lo4;
                ushort* hp = &hi4.x; ushort* lp = &lo4.x;
#pragma unroll
                for (int j = 0; j < 4; ++j) {
                    float wv = fmaf(LR_OVER_B, du[j], wreg[tile][j]);
                    wreg[tile][j] = wv;
                    ushort hb = f32_to_bf16u(wv);
                    hp[j] = hb;
                    lp[j] = f32_to_bf16u(wv - bf16u_to_f32(hb));
                }
                const int si = (fr << 10) | (d ^ fsw);
                *(ushort4*)&wh[si] = hi4;
                *(ushort4*)&wl[si] = lo4;
            }
        }

        __syncthreads();   // barrier 2: wh/wl consistent for next fwd
    }

    // ---- write trace (registers) to d_out [B,H] ----
#pragma unroll
    for (int j = 0; j < 4; ++j) {
        int b = w * 16 + rq + j;
        out[(size_t)b * HID + h0 + fr] = trc[j];
    }
}

// ---------------- fallback fp32 kernels (round-0, small ws) ---------------
#define BK 16
__global__ __launch_bounds__(256) void stdp_fwd_if(
    const float* __restrict__ x, const float* __restrict__ w,
    float* __restrict__ v, float* __restrict__ s, float* __restrict__ trace)
{
    __shared__ float as[BK][64];
    __shared__ float bs[BK][64];
    const int tid = threadIdx.x;
    const int tx = tid & 15, ty = tid >> 4;
    const int b0 = blockIdx.y * 64, h0 = blockIdx.x * 64;
    const int row = tid >> 2, kq = (tid & 3) * 4;
    float acc[4][4] = {};
    for (int k0 = 0; k0 < DIM; k0 += BK) {
        float4 ga = *(const float4*)&x[(size_t)(b0 + row) * DIM + k0 + kq];
        float4 gb = *(const float4*)&w[(size_t)(h0 + row) * DIM + k0 + kq];
        __syncthreads();
        as[kq + 0][row] = ga.x; as[kq + 1][row] = ga.y;
        as[kq + 2][row] = ga.z; as[kq + 3][row] = ga.w;
        bs[kq + 0][row] = gb.x; bs[kq + 1][row] = gb.y;
        bs[kq + 2][row] = gb.z; bs[kq + 3][row] = gb.w;
        __syncthreads();
#pragma unroll
        for (int kk = 0; kk < BK; ++kk) {
            float4 af = *(const float4*)&as[kk][ty * 4];
            float4 bf = *(const float4*)&bs[kk][tx * 4];
            float av[4] = {af.x, af.y, af.z, af.w};
            float bv[4] = {bf.x, bf.y, bf.z, bf.w};
#pragma unroll
            for (int m = 0; m < 4; ++m)
#pragma unroll
                for (int n = 0; n < 4; ++n)
                    acc[m][n] = fmaf(av[m], bv[n], acc[m][n]);
        }
    }
#pragma unroll
    for (int m = 0; m < 4; ++m) {
        size_t idx = (size_t)(b0 + ty * 4 + m) * HID + h0 + tx * 4;
        float4 vv = *(float4*)&v[idx];
        float4 tr = *(float4*)&trace[idx];
        float4 sv;
        float* vvp = &vv.x; float* trp = &tr.x; float* svp = &sv.x;
#pragma unroll
        for (int n = 0; n < 4; ++n) {
            float nv = vvp[n] + acc[m][n];
            float sp = (nv >= 1.0f) ? 1.0f : 0.0f;
            vvp[n] = (nv >= 1.0f) ? 0.0f : nv;
            svp[n] = sp; trp[n] += sp;
        }
        *(float4*)&v[idx] = vv;
        *(float4*)&s[idx] = sv;
        *(float4*)&trace[idx] = tr;
    }
}

__global__ __launch_bounds__(256) void stdp_wupd(
    const float* __restrict__ x, const float* __restrict__ s,
    float* __restrict__ w)
{
    __shared__ float ss[BK][64];
    __shared__ float xs[BK][64];
    const int tid = threadIdx.x;
    const int tx = tid & 15, ty = tid >> 4;
    const int h0 = blockIdx.y * 64, d0 = blockIdx.x * 64;
    const int krow = tid >> 4, c4 = (tid & 15) * 4;
    float acc[4][4] = {};
    for (int bk0 = 0; bk0 < BATCH; bk0 += BK) {
        float4 gs = *(const float4*)&s[(size_t)(bk0 + krow) * HID + h0 + c4];
        float4 gx = *(const float4*)&x[(size_t)(bk0 + krow) * DIM + d0 + c4];
        __syncthreads();
        *(float4*)&ss[krow][c4] = gs;
        *(float4*)&xs[krow][c4] = gx;
        __syncthreads();
#pragma unroll
        for (int kk = 0; kk < BK; ++kk) {
            float4 af = *(const float4*)&ss[kk][ty * 4];
            float4 bf = *(const float4*)&xs[kk][tx * 4];
            float av[4] = {af.x, af.y, af.z, af.w};
            float bv[4] = {bf.x, bf.y, bf.z, bf.w};
#pragma unroll
            for (int m = 0; m < 4; ++m)
#pragma unroll
                for (int n = 0; n < 4; ++n)
                    acc[m][n] = fmaf(av[m], bv[n], acc[m][n]);
        }
    }
#pragma unroll
    for (int m = 0; m < 4; ++m) {
        size_t idx = (size_t)(h0 + ty * 4 + m) * DIM + d0 + tx * 4;
        float4 wv = *(float4*)&w[idx];
        wv.x = fmaf(LR_OVER_B, acc[m][0], wv.x);
        wv.y = fmaf(LR_OVER_B, acc[m][1], wv.y);
        wv.z = fmaf(LR_OVER_B, acc[m][2], wv.z);
        wv.w = fmaf(LR_OVER_B, acc[m][3], wv.w);
        *(float4*)&w[idx] = wv;
    }
}

extern "C" void kernel_launch(void* const* d_in, const int* in_sizes, int n_in,
                              void* d_out, int out_size, void* d_ws, size_t ws_size,
                              hipStream_t stream) {
    (void)in_sizes; (void)n_in;
    const float* x_seq  = (const float*)d_in[0];   // [T, B, D]
    const float* weight = (const float*)d_in[1];   // [H, D]
    float* out = (float*)d_out;                    // [B, H]

    const size_t WN = (size_t)HID * DIM;
    const size_t BH = (size_t)BATCH * HID;
    const size_t XN = (size_t)T_STEPS * BATCH * DIM;  // 13107200

    const size_t need = 4 * XN * 2;                // xh | xl | xTh | xTl

    if (ws_size >= need) {
        ushort* xh  = (ushort*)d_ws;
        ushort* xl  = xh + XN;
        ushort* xTh = xl + XN;
        ushort* xTl = xTh + XN;

        prep_x<<<dim3(DIM / 32, BATCH / 32, T_STEPS), 256, 0, stream>>>(
            x_seq, xh, xl, xTh, xTl);

        hipFuncSetAttribute(reinterpret_cast<const void*>(&stdp_persistent),
                            hipFuncAttributeMaxDynamicSharedMemorySize,
                            SMEM_BYTES);
        stdp_persistent<<<HID / HT, 1024, SMEM_BYTES, stream>>>(
            xh, xl, xTh, xTl, weight, out);
    } else {
        // fallback: fp32 VALU path (needs ~12.6 MB)
        float* w = (float*)d_ws;
        float* v = w + WN;
        float* s = v + BH;
        hipMemcpyAsync(w, weight, WN * 4, hipMemcpyDeviceToDevice, stream);
        hipMemsetAsync(v, 0, BH * 4, stream);
        hipMemsetAsync(out, 0, (size_t)out_size * 4, stream);
        dim3 blkA(256), grdA(HID / 64, BATCH / 64);
        dim3 blkB(256), grdB(DIM / 64, HID / 64);
        for (int t = 0; t < T_STEPS; ++t) {
            const float* xt = x_seq + (size_t)t * BATCH * DIM;
            stdp_fwd_if<<<grdA, blkA, 0, stream>>>(xt, w, v, s, out);
            if (t < T_STEPS - 1) {
                stdp_wupd<<<grdB, blkB, 0, stream>>>(xt, s, w);
            }
        }
    }
}

// Round 8
// 2880.162 us; speedup vs baseline: 1.1305x; 1.0146x over previous
//
#include <hip/hip_runtime.h>
#include <hip/hip_bf16.h>

// STDP IF-neuron network, T=50 sequential steps. Persistent-kernel v5.
// x_seq [50,256,1024] f32, weight [2048,1024] f32 -> spike_trace [256,2048] f32.
//
// 128 blocks x 512 thr (8 waves); block owns a 16-h slab for all 50 steps.
// W bf16 hi/lo splits in LDS (XOR-swizzled, 64 KB); W fp32 master in
// registers (8x f32x4/thread); v, trace in registers; s in LDS (8 KB).
//
// HARD-WON LESSONS (rounds 5-7): 1024-thr blocks always get a 64-VGPR
// allocation (compiler can't see dynamic LDS -> assumes 2 blocks/CU ->
// 8 waves/SIMD cap) and spill (WRITE_SIZE 23-42 MB of scratch). 512-thr
// blocks empirically get 120-128 VGPRs. With 128 blocks on 256 CUs there
// is <=1 block/CU, so register use up to ~128 costs NOTHING. The real
// floor is the per-XCD L2 x-stream (16 blocks x 3MB/step / 4.3 TB/s
// ~ 11 us/step); compute is ~1.3 us/step. So: no spills, modest load
// depth, single-buffered groups, bounded liveness.
//
// fwd:  wave owns 32 b-rows = 2 sequential 16-b-tile passes; per pass,
//       8 single-buffered groups of 4 k-chunks (8 loads in flight).
// wupd: wave owns 128 d-rows = 8 d-tiles; per tile 2 half-groups of 4
//       b-chunks; sched_barrier(0) per tile stops cross-tile hoisting
//       (tile loop must fully unroll for static wreg[] indexing).
// Product set and accumulation order identical to rounds 2-7 -> bit-
// identical output (absmax 1.0 regime preserved).

#define T_STEPS 50
#define BATCH   256
#define DIM     1024
#define HID     2048
#define HT      16
#define LR_OVER_B (0.005f / 256.0f)

// LDS: wh u16[16][1024] swz | wl u16[16][1024] swz | s u16[16][256] swz
#define SMEM_BYTES (32768 + 32768 + 8192)

typedef __attribute__((ext_vector_type(8))) short short8v;
typedef __attribute__((ext_vector_type(4))) float f32x4;

static __device__ __forceinline__ ushort f32_to_bf16u(float f) {
    __hip_bfloat16 h = __float2bfloat16(f);
    return __builtin_bit_cast(unsigned short, h);
}
static __device__ __forceinline__ float bf16u_to_f32(ushort u) {
    __hip_bfloat16 h = __builtin_bit_cast(__hip_bfloat16, u);
    return __bfloat162float(h);
}

#define MFMA_B16 __builtin_amdgcn_mfma_f32_16x16x32_bf16

// ---------------- prep: row-major + transposed bf16 splits of x -----------
__global__ __launch_bounds__(256) void prep_x(
    const float* __restrict__ x,
    ushort* __restrict__ xh,  ushort* __restrict__ xl,    // [T,B,D]
    ushort* __restrict__ xTh, ushort* __restrict__ xTl)   // [T,D,B]
{
    __shared__ float tile[32][33];
    const int t  = blockIdx.z;
    const int d0 = blockIdx.x * 32;
    const int b0 = blockIdx.y * 32;
    const int tx = threadIdx.x & 31;
    const int ty = threadIdx.x >> 5;         // 0..7
    const float* xt = x + (size_t)t * BATCH * DIM;
    ushort* xht = xh + (size_t)t * BATCH * DIM;
    ushort* xlt = xl + (size_t)t * BATCH * DIM;
#pragma unroll
    for (int r = 0; r < 32; r += 8) {
        size_t gi = (size_t)(b0 + ty + r) * DIM + d0 + tx;
        float v = xt[gi];
        tile[ty + r][tx] = v;
        ushort hi = f32_to_bf16u(v);
        xht[gi] = hi;
        xlt[gi] = f32_to_bf16u(v - bf16u_to_f32(hi));
    }
    __syncthreads();
    ushort* oth = xTh + (size_t)t * DIM * BATCH;
    ushort* otl = xTl + (size_t)t * DIM * BATCH;
#pragma unroll
    for (int r = 0; r < 32; r += 8) {
        float v = tile[tx][ty + r];          // d = d0+ty+r, b = b0+tx
        ushort hi = f32_to_bf16u(v);
        size_t gi = (size_t)(d0 + ty + r) * BATCH + b0 + tx;
        oth[gi] = hi;
        otl[gi] = f32_to_bf16u(v - bf16u_to_f32(hi));
    }
}

// ---------------- THE persistent kernel -----------------------------------
__global__ __launch_bounds__(512, 2) void stdp_persistent(
    const ushort* __restrict__ xh,  const ushort* __restrict__ xl,   // [T,B,D]
    const ushort* __restrict__ xTh, const ushort* __restrict__ xTl,  // [T,D,B]
    const float* __restrict__ weight,                                 // [H,D]
    float* __restrict__ out)                                          // [B,H]
{
    extern __shared__ char smem[];
    ushort* wh = (ushort*)smem;                    // [16][1024] swizzled
    ushort* wl = (ushort*)(smem + 32768);          // [16][1024] swizzled
    ushort* sl = (ushort*)(smem + 65536);          // [16][256]  swizzled

    const int tid  = threadIdx.x;
    const int lane = tid & 63;
    const int w    = tid >> 6;                     // wave 0..7
    const int h0   = blockIdx.x * HT;

    const int fr  = lane & 15;                     // fragment row / h index
    const int kg  = (lane >> 4) * 8;               // fragment k-group offset
    const int rq  = (lane >> 4) * 4;               // D-fragment row base
    const int fsw = (fr & 7) << 3;                 // LDS XOR swizzle

    // ---- init: W master -> registers; bf16 splits -> swizzled LDS ----
    // lane owns h = h0+fr, d = w*128 + tile*16 + rq + {0..3}, tile 0..7
    f32x4 wreg[8];
#pragma unroll
    for (int tile = 0; tile < 8; ++tile) {
        const int d = w * 128 + tile * 16 + rq;
        float4 wv = *(const float4*)&weight[(size_t)(h0 + fr) * DIM + d];
        wreg[tile][0] = wv.x; wreg[tile][1] = wv.y;
        wreg[tile][2] = wv.z; wreg[tile][3] = wv.w;
        ushort4 hi4, lo4;
        ushort* hp = &hi4.x; ushort* lp = &lo4.x;
        const float* p = &wv.x;
#pragma unroll
        for (int e = 0; e < 4; ++e) {
            ushort hb = f32_to_bf16u(p[e]);
            hp[e] = hb;
            lp[e] = f32_to_bf16u(p[e] - bf16u_to_f32(hb));
        }
        const int sidx = (fr << 10) | (d ^ fsw);
        *(ushort4*)&wh[sidx] = hi4;
        *(ushort4*)&wl[sidx] = lo4;
    }
    __syncthreads();

    const f32x4 z4 = {0.f, 0.f, 0.f, 0.f};
    f32x4 vmem[2] = {z4, z4};
    f32x4 trc[2]  = {z4, z4};

    for (int t = 0; t < T_STEPS; ++t) {
        const ushort* xht = xh + (size_t)t * BATCH * DIM;
        const ushort* xlt = xl + (size_t)t * BATCH * DIM;

        // ================= fwd: mem = x @ W^T (3-product split) ===========
        // wave w owns b rows [32w, 32w+32): two sequential 16-b-tile passes.
#pragma unroll
        for (int bt = 0; bt < 2; ++bt) {
            f32x4 acc = z4;
            const size_t r0 = (size_t)(w * 32 + bt * 16 + fr) * DIM + kg;

            short8v GA[4][2];   // single-buffered: 4 k-chunks, hi/lo

#pragma unroll 1
            for (int g = 0; g < 8; ++g) {
                const int kbase = g * 128;
#pragma unroll
                for (int c = 0; c < 4; ++c) {
                    const int kk = kbase + c * 32;
                    GA[c][0] = *(const short8v*)&xht[r0 + kk];
                    GA[c][1] = *(const short8v*)&xlt[r0 + kk];
                }
#pragma unroll
                for (int c = 0; c < 4; ++c) {
                    const int kk = kbase + c * 32;
                    const int bi = (fr << 10) | ((kk + kg) ^ fsw);
                    short8v bh = *(const short8v*)&wh[bi];
                    short8v bl = *(const short8v*)&wl[bi];
                    acc = MFMA_B16(GA[c][0], bh, acc, 0, 0, 0);
                    acc = MFMA_B16(GA[c][0], bl, acc, 0, 0, 0);
                    acc = MFMA_B16(GA[c][1], bh, acc, 0, 0, 0);
                }
            }

            // ---- fused IF update + packed spike store (D: row=b, col=h) --
            const int bb = w * 32 + bt * 16 + rq;
            ushort4 sq; ushort* sp = &sq.x;
#pragma unroll
            for (int j = 0; j < 4; ++j) {
                float nv = vmem[bt][j] + acc[j];
                bool fire = (nv >= 1.0f);
                vmem[bt][j] = fire ? 0.0f : nv;
                trc[bt][j] += fire ? 1.0f : 0.0f;
                sp[j] = fire ? (ushort)0x3F80 : (ushort)0;
            }
            *(ushort4*)&sl[(fr << 8) | (bb ^ fsw)] = sq;
        }

        __syncthreads();   // barrier 1: s complete; fwd W-reads done

        // ================= wupd: dwT = xT @ s^T, W += lr/B * dw ===========
        // wave w owns d rows [128w, 128w+128) = 8 d-tiles of 16.
        if (t < T_STEPS - 1) {
            const ushort* xTht = xTh + (size_t)t * DIM * BATCH;
            const ushort* xTlt = xTl + (size_t)t * DIM * BATCH;

            short8v HA[4][2];   // half-group: 4 b-chunks, hi/lo

#pragma unroll
            for (int tile = 0; tile < 8; ++tile) {
                f32x4 du = z4;
                const size_t drow = (size_t)(w * 128 + tile * 16 + fr) * BATCH;
#pragma unroll 1
                for (int half = 0; half < 2; ++half) {
#pragma unroll
                    for (int c2 = 0; c2 < 4; ++c2) {
                        const size_t gi = drow + (half * 4 + c2) * 32 + kg;
                        HA[c2][0] = *(const short8v*)&xTht[gi];
                        HA[c2][1] = *(const short8v*)&xTlt[gi];
                    }
#pragma unroll
                    for (int c2 = 0; c2 < 4; ++c2) {
                        const int c = half * 4 + c2;
                        short8v sf = *(const short8v*)&sl[(fr << 8) | ((c * 32 + kg) ^ fsw)];
                        du = MFMA_B16(HA[c2][0], sf, du, 0, 0, 0);
                        du = MFMA_B16(HA[c2][1], sf, du, 0, 0, 0);
                    }
                }
                // ---- W update + re-split (D: row=d, col=h=fr) ----
                const int d = w * 128 + tile * 16 + rq;
                ushort4 hi4, lo4;
                ushort* hp = &hi4.x; ushort* lp = &lo4.x;
#pragma unroll
                for (int j = 0; j < 4; ++j) {
                    float wv = fmaf(LR_OVER_B, du[j], wreg[tile][j]);
                    wreg[tile][j] = wv;
                    ushort hb = f32_to_bf16u(wv);
                    hp[j] = hb;
                    lp[j] = f32_to_bf16u(wv - bf16u_to_f32(hb));
                }
                const int si = (fr << 10) | (d ^ fsw);
                *(ushort4*)&wh[si] = hi4;
                *(ushort4*)&wl[si] = lo4;
                // pin scheduling: no cross-tile load hoisting (bounds VGPR
                // liveness; tile loop must stay unrolled for static wreg[])
                __builtin_amdgcn_sched_barrier(0);
            }
        }

        __syncthreads();   // barrier 2: wh/wl consistent for next fwd
    }

    // ---- write trace (registers) to d_out [B,H] ----
#pragma unroll
    for (int bt = 0; bt < 2; ++bt) {
#pragma unroll
        for (int j = 0; j < 4; ++j) {
            int b = w * 32 + bt * 16 + rq + j;
            out[(size_t)b * HID + h0 + fr] = trc[bt][j];
        }
    }
}

// ---------------- fallback fp32 kernels (round-0, small ws) ---------------
#define BK 16
__global__ __launch_bounds__(256) void stdp_fwd_if(
    const float* __restrict__ x, const float* __restrict__ w,
    float* __restrict__ v, float* __restrict__ s, float* __restrict__ trace)
{
    __shared__ float as[BK][64];
    __shared__ float bs[BK][64];
    const int tid = threadIdx.x;
    const int tx = tid & 15, ty = tid >> 4;
    const int b0 = blockIdx.y * 64, h0 = blockIdx.x * 64;
    const int row = tid >> 2, kq = (tid & 3) * 4;
    float acc[4][4] = {};
    for (int k0 = 0; k0 < DIM; k0 += BK) {
        float4 ga = *(const float4*)&x[(size_t)(b0 + row) * DIM + k0 + kq];
        float4 gb = *(const float4*)&w[(size_t)(h0 + row) * DIM + k0 + kq];
        __syncthreads();
        as[kq + 0][row] = ga.x; as[kq + 1][row] = ga.y;
        as[kq + 2][row] = ga.z; as[kq + 3][row] = ga.w;
        bs[kq + 0][row] = gb.x; bs[kq + 1][row] = gb.y;
        bs[kq + 2][row] = gb.z; bs[kq + 3][row] = gb.w;
        __syncthreads();
#pragma unroll
        for (int kk = 0; kk < BK; ++kk) {
            float4 af = *(const float4*)&as[kk][ty * 4];
            float4 bf = *(const float4*)&bs[kk][tx * 4];
            float av[4] = {af.x, af.y, af.z, af.w};
            float bv[4] = {bf.x, bf.y, bf.z, bf.w};
#pragma unroll
            for (int m = 0; m < 4; ++m)
#pragma unroll
                for (int n = 0; n < 4; ++n)
                    acc[m][n] = fmaf(av[m], bv[n], acc[m][n]);
        }
    }
#pragma unroll
    for (int m = 0; m < 4; ++m) {
        size_t idx = (size_t)(b0 + ty * 4 + m) * HID + h0 + tx * 4;
        float4 vv = *(float4*)&v[idx];
        float4 tr = *(float4*)&trace[idx];
        float4 sv;
        float* vvp = &vv.x; float* trp = &tr.x; float* svp = &sv.x;
#pragma unroll
        for (int n = 0; n < 4; ++n) {
            float nv = vvp[n] + acc[m][n];
            float sp = (nv >= 1.0f) ? 1.0f : 0.0f;
            vvp[n] = (nv >= 1.0f) ? 0.0f : nv;
            svp[n] = sp; trp[n] += sp;
        }
        *(float4*)&v[idx] = vv;
        *(float4*)&s[idx] = sv;
        *(float4*)&trace[idx] = tr;
    }
}

__global__ __launch_bounds__(256) void stdp_wupd(
    const float* __restrict__ x, const float* __restrict__ s,
    float* __restrict__ w)
{
    __shared__ float ss[BK][64];
    __shared__ float xs[BK][64];
    const int tid = threadIdx.x;
    const int tx = tid & 15, ty = tid >> 4;
    const int h0 = blockIdx.y * 64, d0 = blockIdx.x * 64;
    const int krow = tid >> 4, c4 = (tid & 15) * 4;
    float acc[4][4] = {};
    for (int bk0 = 0; bk0 < BATCH; bk0 += BK) {
        float4 gs = *(const float4*)&s[(size_t)(bk0 + krow) * HID + h0 + c4];
        float4 gx = *(const float4*)&x[(size_t)(bk0 + krow) * DIM + d0 + c4];
        __syncthreads();
        *(float4*)&ss[krow][c4] = gs;
        *(float4*)&xs[krow][c4] = gx;
        __syncthreads();
#pragma unroll
        for (int kk = 0; kk < BK; ++kk) {
            float4 af = *(const float4*)&ss[kk][ty * 4];
            float4 bf = *(const float4*)&xs[kk][tx * 4];
            float av[4] = {af.x, af.y, af.z, af.w};
            float bv[4] = {bf.x, bf.y, bf.z, bf.w};
#pragma unroll
            for (int m = 0; m < 4; ++m)
#pragma unroll
                for (int n = 0; n < 4; ++n)
                    acc[m][n] = fmaf(av[m], bv[n], acc[m][n]);
        }
    }
#pragma unroll
    for (int m = 0; m < 4; ++m) {
        size_t idx = (size_t)(h0 + ty * 4 + m) * DIM + d0 + tx * 4;
        float4 wv = *(float4*)&w[idx];
        wv.x = fmaf(LR_OVER_B, acc[m][0], wv.x);
        wv.y = fmaf(LR_OVER_B, acc[m][1], wv.y);
        wv.z = fmaf(LR_OVER_B, acc[m][2], wv.z);
        wv.w = fmaf(LR_OVER_B, acc[m][3], wv.w);
        *(float4*)&w[idx] = wv;
    }
}

extern "C" void kernel_launch(void* const* d_in, const int* in_sizes, int n_in,
                              void* d_out, int out_size, void* d_ws, size_t ws_size,
                              hipStream_t stream) {
    (void)in_sizes; (void)n_in;
    const float* x_seq  = (const float*)d_in[0];   // [T, B, D]
    const float* weight = (const float*)d_in[1];   // [H, D]
    float* out = (float*)d_out;                    // [B, H]

    const size_t WN = (size_t)HID * DIM;
    const size_t BH = (size_t)BATCH * HID;
    const size_t XN = (size_t)T_STEPS * BATCH * DIM;  // 13107200

    const size_t need = 4 * XN * 2;                // xh | xl | xTh | xTl

    if (ws_size >= need) {
        ushort* xh  = (ushort*)d_ws;
        ushort* xl  = xh + XN;
        ushort* xTh = xl + XN;
        ushort* xTl = xTh + XN;

        prep_x<<<dim3(DIM / 32, BATCH / 32, T_STEPS), 256, 0, stream>>>(
            x_seq, xh, xl, xTh, xTl);

        hipFuncSetAttribute(reinterpret_cast<const void*>(&stdp_persistent),
                            hipFuncAttributeMaxDynamicSharedMemorySize,
                            SMEM_BYTES);
        stdp_persistent<<<HID / HT, 512, SMEM_BYTES, stream>>>(
            xh, xl, xTh, xTl, weight, out);
    } else {
        // fallback: fp32 VALU path (needs ~12.6 MB)
        float* w = (float*)d_ws;
        float* v = w + WN;
        float* s = v + BH;
        hipMemcpyAsync(w, weight, WN * 4, hipMemcpyDeviceToDevice, stream);
        hipMemsetAsync(v, 0, BH * 4, stream);
        hipMemsetAsync(out, 0, (size_t)out_size * 4, stream);
        dim3 blkA(256), grdA(HID / 64, BATCH / 64);
        dim3 blkB(256), grdB(DIM / 64, HID / 64);
        for (int t = 0; t < T_STEPS; ++t) {
            const float* xt = x_seq + (size_t)t * BATCH * DIM;
            stdp_fwd_if<<<grdA, blkA, 0, stream>>>(xt, w, v, s, out);
            if (t < T_STEPS - 1) {
                stdp_wupd<<<grdB, blkB, 0, stream>>>(xt, s, w);
            }
        }
    }
}